// Round 3
// baseline (1547.306 us; speedup 1.0000x reference)
//
#include <hip/hip_runtime.h>
#include <hip/hip_bf16.h>

// Problem constants
constexpr int B_ = 2;
constexpr int C_ = 256;
constexpr int S_TOT = 48 * 48;   // 2304
constexpr int HEADS_ = 8;
#define INV_SQRT_DH 0.17677669529663688f

// ---------------------------------------------------------------------------
// Kernel 1: MLP layer  out[b][s][co] = relu( sum_ci in[b][s][ci]*W[ci][co] + bias[co] )
// IN_MODE 0: in is [B][C][S]; IN_MODE 1: in is [B][S][C]
// ---------------------------------------------------------------------------
template<int IN_MODE>
__global__ __launch_bounds__(256) void k_mlp(const float* __restrict__ in,
                                             const float* __restrict__ Wm,
                                             const float* __restrict__ bias,
                                             float* __restrict__ out) {
  __shared__ __align__(16) float in_s[32][260];
  const int tid = threadIdx.x;
  const int s0 = blockIdx.x * 32;
  const int b  = blockIdx.y;

  if (IN_MODE == 0) {
    for (int idx = tid; idx < 32 * 256; idx += 256) {
      int ci = idx >> 5, r = idx & 31;
      in_s[r][ci] = in[((size_t)b * C_ + ci) * S_TOT + s0 + r];
    }
  } else {
    for (int idx = tid; idx < 32 * 256; idx += 256) {
      int r = idx >> 8, ci = idx & 255;
      in_s[r][ci] = in[((size_t)b * S_TOT + s0 + r) * C_ + ci];
    }
  }
  __syncthreads();

  const int co = tid;
  float acc[32];
#pragma unroll
  for (int r = 0; r < 32; ++r) acc[r] = 0.f;

  for (int c4 = 0; c4 < 64; ++c4) {
    const float w0 = Wm[(c4 * 4 + 0) * C_ + co];
    const float w1 = Wm[(c4 * 4 + 1) * C_ + co];
    const float w2 = Wm[(c4 * 4 + 2) * C_ + co];
    const float w3 = Wm[(c4 * 4 + 3) * C_ + co];
#pragma unroll
    for (int r = 0; r < 32; ++r) {
      float4 a = *(const float4*)&in_s[r][c4 * 4];
      acc[r] = fmaf(a.x, w0, fmaf(a.y, w1, fmaf(a.z, w2, fmaf(a.w, w3, acc[r]))));
    }
  }

  const float bi = bias[co];
#pragma unroll 4
  for (int r = 0; r < 32; ++r) {
    out[((size_t)b * S_TOT + s0 + r) * C_ + co] = fmaxf(acc[r] + bi, 0.f);
  }
}

// ---------------------------------------------------------------------------
// Kernel 2: fused scores = (Q.K^T)/sqrt(dh) for all 8 heads, top-1-over-heads
// masking, masked-score write to probs region, online per-row softmax stats.
// grid (36 i-tiles, 4 j-chunks, B), block 256, 64x64 tile, micro 4x4/thread.
// LDS 80 KiB: Q full tile (64x256, staged once) + K quarter tile (64x64,
// streamed 4x per j-tile) -> 2 blocks/CU, 8 waves/CU.
// ---------------------------------------------------------------------------
__global__ __launch_bounds__(256, 2) void k_scores(const float* __restrict__ Qp,
                                                   const float* __restrict__ Kp,
                                                   float* __restrict__ probs,
                                                   float* __restrict__ st_m,
                                                   float* __restrict__ st_z) {
  __shared__ __align__(16) float q_s[64 * 256];  // 64 KiB
  __shared__ __align__(16) float k_s[64 * 64];   // 16 KiB
  const int tid = threadIdx.x;
  const int i0 = blockIdx.x * 64;
  const int js = blockIdx.y;          // 0..3, chunk of 576 j's
  const int b  = blockIdx.z;
  const int jbase = js * 576;
  const int iq = tid >> 4;            // 0..15
  const int jq = tid & 15;            // 0..15

  // stage Q full tile once (swizzle: low 3 bits of float4-unit index ^ (row&7))
  for (int idx = tid; idx < 64 * 64; idx += 256) {
    int r = idx >> 6, c4 = idx & 63;
    float4 v = *(const float4*)(Qp + ((size_t)b * S_TOT + i0 + r) * C_ + c4 * 4);
    int c4s = (c4 & ~7) | ((c4 & 7) ^ (r & 7));
    *(float4*)&q_s[r * 256 + c4s * 4] = v;
  }

  float m_st[4][8], z_st[4][8];
#pragma unroll
  for (int v = 0; v < 4; ++v)
#pragma unroll
    for (int h = 0; h < 8; ++h) { m_st[v][h] = -1e18f; z_st[v][h] = 0.f; }

  for (int jt = 0; jt < 9; ++jt) {
    const int j0 = jbase + jt * 64;

    float sacc[4][4][8];
#pragma unroll
    for (int v = 0; v < 4; ++v)
#pragma unroll
      for (int u = 0; u < 4; ++u)
#pragma unroll
        for (int h = 0; h < 8; ++h) sacc[v][u][h] = 0.f;

#pragma unroll
    for (int cq = 0; cq < 4; ++cq) {
      __syncthreads();
      // stage K quarter: 64 rows x 64 floats (heads 2cq, 2cq+1)
      for (int e = tid; e < 1024; e += 256) {
        int r = e >> 4, c4k = e & 15;
        float4 v = *(const float4*)(Kp + ((size_t)b * S_TOT + j0 + r) * C_ + cq * 64 + c4k * 4);
        int c4s = (c4k & 8) | ((c4k & 7) ^ (r & 7));
        *(float4*)&k_s[r * 64 + c4s * 4] = v;
      }
      __syncthreads();

#pragma unroll
      for (int h2 = 0; h2 < 2; ++h2) {
        const int h = cq * 2 + h2;
#pragma unroll
        for (int cc = 0; cc < 8; ++cc) {
          float4 qv[4], kv[4];
#pragma unroll
          for (int v = 0; v < 4; ++v) {
            int r = iq + 16 * v;
            int c4s = (h * 8) | (cc ^ (r & 7));
            qv[v] = *(const float4*)&q_s[r * 256 + c4s * 4];
          }
#pragma unroll
          for (int u = 0; u < 4; ++u) {
            int r = jq + 16 * u;
            int c4s = (h2 * 8) | (cc ^ (r & 7));
            kv[u] = *(const float4*)&k_s[r * 64 + c4s * 4];
          }
#pragma unroll
          for (int v = 0; v < 4; ++v)
#pragma unroll
            for (int u = 0; u < 4; ++u) {
              sacc[v][u][h] = fmaf(qv[v].x, kv[u].x,
                               fmaf(qv[v].y, kv[u].y,
                                 fmaf(qv[v].z, kv[u].z,
                                   fmaf(qv[v].w, kv[u].w, sacc[v][u][h]))));
            }
        }
      }
    }

    // epilogue: scale, head-max threshold, mask, store, online stats (1 exp)
#pragma unroll
    for (int v = 0; v < 4; ++v) {
      const int i = i0 + iq + 16 * v;
#pragma unroll
      for (int u = 0; u < 4; ++u) {
        const int j = j0 + jq + 16 * u;
        float sc[8];
        float thr = -1e30f;
#pragma unroll
        for (int h = 0; h < 8; ++h) {
          sc[h] = sacc[v][u][h] * INV_SQRT_DH;
          thr = fmaxf(thr, sc[h]);
        }
#pragma unroll
        for (int h = 0; h < 8; ++h) {
          float mv = sc[h] < thr ? -1e18f : sc[h];
          probs[((size_t)((b * 8 + h) * S_TOT + i)) * S_TOT + j] = mv;
          float om = m_st[v][h];
          float d = mv - om;
          bool up = d > 0.f;
          float e = __expf(up ? -d : d);
          float z = z_st[v][h];
          z_st[v][h] = up ? fmaf(z, e, 1.f) : z + e;
          m_st[v][h] = up ? mv : om;
        }
      }
    }
  }

  // reduce stats across the 16 jq lanes
#pragma unroll
  for (int v = 0; v < 4; ++v) {
#pragma unroll
    for (int h = 0; h < 8; ++h) {
      float m = m_st[v][h], z = z_st[v][h];
#pragma unroll
      for (int off = 8; off >= 1; off >>= 1) {
        float m2 = __shfl_xor(m, off, 16);
        float z2 = __shfl_xor(z, off, 16);
        float nm = fmaxf(m, m2);
        z = fmaf(z, __expf(m - nm), z2 * __expf(m2 - nm));
        m = nm;
      }
      if (jq == 0) {
        const int i = i0 + iq + 16 * v;
        size_t sidx = ((size_t)(js * B_ + b) * HEADS_ + h) * S_TOT + i;
        st_m[sidx] = m;
        st_z[sidx] = z;
      }
    }
  }
}

// ---------------------------------------------------------------------------
// Kernel 3: finalize probs = exp(s - m)/Z (in-place), ctx = probs @ V.
// grid (144 i-tiles, 8 heads, B), block 256.
// ---------------------------------------------------------------------------
__global__ __launch_bounds__(256) void k_probs_pv(const float* __restrict__ Vp,
                                                  const float* __restrict__ st_m,
                                                  const float* __restrict__ st_z,
                                                  float* __restrict__ probs,
                                                  float* __restrict__ ctx) {
  __shared__ __align__(16) float v_s[32][36];
  __shared__ __align__(16) float p_s[16][36];
  __shared__ float row_m[16], row_iz[16];
  __shared__ __align__(16) float ctx_red[8][16][32];
  const int tid = threadIdx.x;
  const int i0 = blockIdx.x * 16;
  const int h  = blockIdx.y;
  const int b  = blockIdx.z;

  if (tid < 16) {
    const int i = i0 + tid;
    float mm[4], zz[4];
#pragma unroll
    for (int js = 0; js < 4; ++js) {
      size_t sidx = ((size_t)(js * B_ + b) * HEADS_ + h) * S_TOT + i;
      mm[js] = st_m[sidx];
      zz[js] = st_z[sidx];
    }
    float M = fmaxf(fmaxf(mm[0], mm[1]), fmaxf(mm[2], mm[3]));
    float Z = zz[0] * __expf(mm[0] - M) + zz[1] * __expf(mm[1] - M) +
              zz[2] * __expf(mm[2] - M) + zz[3] * __expf(mm[3] - M);
    row_m[tid] = M;
    row_iz[tid] = 1.0f / Z;
  }
  __syncthreads();

  const int il = tid >> 5;        // phase A: 0..7
  const int jl = tid & 31;
  const int d4 = tid & 7;         // phase B
  const int ip = (tid >> 3) & 3;
  const int jp = tid >> 5;        // 0..7

  float4 acc[4];
#pragma unroll
  for (int r = 0; r < 4; ++r) acc[r] = make_float4(0.f, 0.f, 0.f, 0.f);

  float* pbase = probs + ((size_t)(b * 8 + h) * S_TOT + i0) * S_TOT;
  const float* vbase = Vp + (size_t)b * S_TOT * C_ + h * 32;

  for (int j0 = 0; j0 < S_TOT; j0 += 32) {
    __syncthreads();
#pragma unroll
    for (int k = 0; k < 4; ++k) {
      int e = tid + k * 256;
      int r = e >> 5, d = e & 31;
      v_s[r][d] = vbase[(size_t)(j0 + r) * C_ + d];
    }
#pragma unroll
    for (int rr = 0; rr < 2; ++rr) {
      int r = il + rr * 8;
      size_t off = (size_t)r * S_TOT + j0 + jl;
      float sv = pbase[off];
      float p = __expf(sv - row_m[r]) * row_iz[r];
      pbase[off] = p;
      p_s[r][jl] = p;
    }
    __syncthreads();
    float4 v4[4];
#pragma unroll
    for (int jj = 0; jj < 4; ++jj) v4[jj] = *(const float4*)&v_s[jp * 4 + jj][d4 * 4];
#pragma unroll
    for (int rq = 0; rq < 4; ++rq) {
      int r = ip + rq * 4;
      float4 p4 = *(const float4*)&p_s[r][jp * 4];
      acc[rq].x = fmaf(p4.x, v4[0].x, fmaf(p4.y, v4[1].x, fmaf(p4.z, v4[2].x, fmaf(p4.w, v4[3].x, acc[rq].x))));
      acc[rq].y = fmaf(p4.x, v4[0].y, fmaf(p4.y, v4[1].y, fmaf(p4.z, v4[2].y, fmaf(p4.w, v4[3].y, acc[rq].y))));
      acc[rq].z = fmaf(p4.x, v4[0].z, fmaf(p4.y, v4[1].z, fmaf(p4.z, v4[2].z, fmaf(p4.w, v4[3].z, acc[rq].z))));
      acc[rq].w = fmaf(p4.x, v4[0].w, fmaf(p4.y, v4[1].w, fmaf(p4.z, v4[2].w, fmaf(p4.w, v4[3].w, acc[rq].w))));
    }
  }

  __syncthreads();
#pragma unroll
  for (int rq = 0; rq < 4; ++rq)
    *(float4*)&ctx_red[jp][ip + rq * 4][d4 * 4] = acc[rq];
  __syncthreads();

  for (int e = tid; e < 512; e += 256) {
    int r = e >> 5, d = e & 31;
    float sum = 0.f;
#pragma unroll
    for (int p = 0; p < 8; ++p) sum += ctx_red[p][r][d];
    ctx[((size_t)(b * C_ + h * 32 + d)) * S_TOT + i0 + r] = sum;
  }
}

// ---------------------------------------------------------------------------
// Kernel 4a: repack conv weights W[co][ci][3][3] -> Wt[ci][k][co]
// ---------------------------------------------------------------------------
__global__ __launch_bounds__(256) void k_repackW(const float* __restrict__ W,
                                                 float* __restrict__ Wt) {
  const int ci = blockIdx.x;
  const int k  = blockIdx.y;
  const int co = threadIdx.x;
  Wt[((size_t)ci * 9 + k) * 256 + co] = W[((size_t)co * 256 + ci) * 9 + k];
}

// ---------------------------------------------------------------------------
// Kernel 4b: 3x3 SAME conv, register micro-tile 4co x 6px per thread.
// ---------------------------------------------------------------------------
template<int DELTA>
__device__ __forceinline__ void conv_inner(const float* __restrict__ w_s,
                                           const float (*__restrict__ in_s)[4][56],
                                           int cog, int colg, int row_t,
                                           float (&acc)[4][6]) {
  const int a0 = 6 * colg + 3 - DELTA;   // 16B-aligned LDS col base
#pragma unroll
  for (int ci = 0; ci < 8; ++ci) {
    float4 wv[9];
#pragma unroll
    for (int k = 0; k < 9; ++k)
      wv[k] = *(const float4*)&w_s[(ci * 9 + k) * 64 + cog * 4];
    float rr[3][12];
#pragma unroll
    for (int r = 0; r < 3; ++r) {
      *(float4*)&rr[r][0] = *(const float4*)&in_s[ci][row_t + r][a0];
      *(float4*)&rr[r][4] = *(const float4*)&in_s[ci][row_t + r][a0 + 4];
      *(float4*)&rr[r][8] = *(const float4*)&in_s[ci][row_t + r][a0 + 8];
    }
#pragma unroll
    for (int ky = 0; ky < 3; ++ky)
#pragma unroll
      for (int kx = 0; kx < 3; ++kx) {
        float4 wk = wv[ky * 3 + kx];
#pragma unroll
        for (int p = 0; p < 6; ++p) {
          float xv = rr[ky][DELTA + p + kx];
          acc[0][p] = fmaf(xv, wk.x, acc[0][p]);
          acc[1][p] = fmaf(xv, wk.y, acc[1][p]);
          acc[2][p] = fmaf(xv, wk.z, acc[2][p]);
          acc[3][p] = fmaf(xv, wk.w, acc[3][p]);
        }
      }
  }
}

template<bool DO_SELU>
__global__ __launch_bounds__(256) void k_conv2(const float* __restrict__ in,
                                               const float* __restrict__ Wt,
                                               const float* __restrict__ bias,
                                               float* __restrict__ out) {
  __shared__ __align__(16) float w_s[8 * 9 * 64];      // 18.4 KB
  __shared__ __align__(16) float in_s[8][4][56];       // 7.2 KB
  const int tid  = threadIdx.x;
  const int w    = tid >> 6;          // wave 0..3
  const int lane = tid & 63;
  const int cog   = lane & 15;                       // 16 co-groups of 4
  const int colg  = ((lane >> 4) << 1) | (w & 1);    // 0..7 (parity wave-uniform)
  const int row_t = w >> 1;                          // 0..1
  const int co0 = blockIdx.x * 64;
  const int r0  = blockIdx.y * 2;
  const int b   = blockIdx.z;

  for (int e = tid; e < 8 * 4 * 8; e += 256) {
    int ci = e >> 5, r = (e >> 3) & 3, c = e & 7;
    in_s[ci][r][c < 4 ? c : 48 + c] = 0.f;
  }

  float acc[4][6];
#pragma unroll
  for (int q = 0; q < 4; ++q)
#pragma unroll
    for (int p = 0; p < 6; ++p) acc[q][p] = 0.f;

  for (int ci0 = 0; ci0 < 256; ci0 += 8) {
    __syncthreads();
    for (int e = tid; e < 1152; e += 256) {
      int co4 = e & 15; int t = e >> 4; int k = t % 9; int ci = t / 9;
      float4 v = *(const float4*)(Wt + (((size_t)(ci0 + ci) * 9 + k) * 256 + co0 + co4 * 4));
      *(float4*)&w_s[(ci * 9 + k) * 64 + co4 * 4] = v;
    }
    for (int e = tid; e < 384; e += 256) {
      int q = e % 12; int r = (e / 12) & 3; int ci = e / 48;
      int gr = r0 - 1 + r;
      float4 v = make_float4(0.f, 0.f, 0.f, 0.f);
      if (gr >= 0 && gr < 48)
        v = *(const float4*)(in + ((size_t)(b * 256 + ci0 + ci) * 48 + gr) * 48 + 4 * q);
      *(float4*)&in_s[ci][r][4 + 4 * q] = v;
    }
    __syncthreads();
    if (w & 1) conv_inner<1>(w_s, in_s, cog, colg, row_t, acc);
    else       conv_inner<3>(w_s, in_s, cog, colg, row_t, acc);
  }

  const int orow = r0 + row_t;
  const int ocol0 = colg * 6;
#pragma unroll
  for (int q = 0; q < 4; ++q) {
    const int co = co0 + cog * 4 + q;
    const float bi = bias[co];
    float* op = out + ((size_t)(b * 256 + co) * 48 + orow) * 48 + ocol0;
#pragma unroll
    for (int p = 0; p < 6; ++p) {
      float y = acc[q][p] + bi;
      if (DO_SELU)
        y = 1.0507009873554805f * (y > 0.f ? y : 1.6732632423543772f * expm1f(y));
      op[p] = y;
    }
  }
}

// ---------------------------------------------------------------------------
extern "C" void kernel_launch(void* const* d_in, const int* in_sizes, int n_in,
                              void* d_out, int out_size, void* d_ws, size_t ws_size,
                              hipStream_t stream) {
  const float* x   = (const float*)d_in[0];
  const float* ref = (const float*)d_in[1];
  const float* qW1 = (const float*)d_in[2];
  const float* qb1 = (const float*)d_in[3];
  const float* qW2 = (const float*)d_in[4];
  const float* qb2 = (const float*)d_in[5];
  const float* kW1 = (const float*)d_in[6];
  const float* kb1 = (const float*)d_in[7];
  const float* kW2 = (const float*)d_in[8];
  const float* kb2 = (const float*)d_in[9];
  const float* vW1 = (const float*)d_in[10];
  const float* vb1 = (const float*)d_in[11];
  const float* vW2 = (const float*)d_in[12];
  const float* vb2 = (const float*)d_in[13];
  const float* c1W = (const float*)d_in[14];
  const float* c1b = (const float*)d_in[15];
  const float* c2W = (const float*)d_in[16];
  const float* c2b = (const float*)d_in[17];

  float* out = (float*)d_out;
  float* probs = out + (size_t)B_ * C_ * S_TOT;       // [B][H][S][S]
  float* ws = (float*)d_ws;
  const size_t BSC = (size_t)B_ * S_TOT * C_;         // 1,179,648
  const size_t STATS = (size_t)4 * B_ * HEADS_ * S_TOT;
  const size_t WTSZ = (size_t)256 * 9 * 256;          // 589,824

  float* Qb  = ws;
  float* Kb  = Qb + BSC;
  float* Vb  = Kb + BSC;
  float* Ht  = Vb + BSC;
  float* stm = Ht + BSC;
  float* stz = stm + STATS;
  float* ctx = stz + STATS;
  float* tmp1 = ctx + BSC;
  float* Wt1 = tmp1 + BSC;
  float* Wt2 = Wt1 + WTSZ;

  dim3 blk(256);
  k_repackW<<<dim3(256, 9), blk, 0, stream>>>(c1W, Wt1);
  k_repackW<<<dim3(256, 9), blk, 0, stream>>>(c2W, Wt2);

  dim3 gmlp(72, B_);
  k_mlp<0><<<gmlp, blk, 0, stream>>>(x,   qW1, qb1, Ht);
  k_mlp<1><<<gmlp, blk, 0, stream>>>(Ht,  qW2, qb2, Qb);
  k_mlp<0><<<gmlp, blk, 0, stream>>>(ref, kW1, kb1, Ht);
  k_mlp<1><<<gmlp, blk, 0, stream>>>(Ht,  kW2, kb2, Kb);
  k_mlp<0><<<gmlp, blk, 0, stream>>>(ref, vW1, vb1, Ht);
  k_mlp<1><<<gmlp, blk, 0, stream>>>(Ht,  vW2, vb2, Vb);

  k_scores<<<dim3(36, 4, B_), blk, 0, stream>>>(Qb, Kb, probs, stm, stz);
  k_probs_pv<<<dim3(144, 8, B_), blk, 0, stream>>>(Vb, stm, stz, probs, ctx);
  k_conv2<true ><<<dim3(4, 24, B_), blk, 0, stream>>>(ctx,  Wt1, c1b, tmp1);
  k_conv2<false><<<dim3(4, 24, B_), blk, 0, stream>>>(tmp1, Wt2, c2b, out);
}

// Round 4
// 1330.000 us; speedup vs baseline: 1.1634x; 1.1634x over previous
//
#include <hip/hip_runtime.h>
#include <hip/hip_bf16.h>

// Problem constants
constexpr int B_ = 2;
constexpr int C_ = 256;
constexpr int S_TOT = 48 * 48;   // 2304
constexpr int HEADS_ = 8;
#define INV_SQRT_DH 0.17677669529663688f

// ---------------------------------------------------------------------------
// Kernel 1: MLP layer  out[b][s][co] = relu( sum_ci in[b][s][ci]*W[ci][co] + b )
// IN_MODE 0: in is [B][C][S]; IN_MODE 1: in is [B][S][C]
// ---------------------------------------------------------------------------
template<int IN_MODE>
__global__ __launch_bounds__(256) void k_mlp(const float* __restrict__ in,
                                             const float* __restrict__ Wm,
                                             const float* __restrict__ bias,
                                             float* __restrict__ out) {
  __shared__ __align__(16) float in_s[32][260];
  const int tid = threadIdx.x;
  const int s0 = blockIdx.x * 32;
  const int b  = blockIdx.y;

  if (IN_MODE == 0) {
    for (int idx = tid; idx < 32 * 256; idx += 256) {
      int ci = idx >> 5, r = idx & 31;
      in_s[r][ci] = in[((size_t)b * C_ + ci) * S_TOT + s0 + r];
    }
  } else {
    for (int idx = tid; idx < 32 * 256; idx += 256) {
      int r = idx >> 8, ci = idx & 255;
      in_s[r][ci] = in[((size_t)b * S_TOT + s0 + r) * C_ + ci];
    }
  }
  __syncthreads();

  const int co = tid;
  float acc[32];
#pragma unroll
  for (int r = 0; r < 32; ++r) acc[r] = 0.f;

  for (int c4 = 0; c4 < 64; ++c4) {
    const float w0 = Wm[(c4 * 4 + 0) * C_ + co];
    const float w1 = Wm[(c4 * 4 + 1) * C_ + co];
    const float w2 = Wm[(c4 * 4 + 2) * C_ + co];
    const float w3 = Wm[(c4 * 4 + 3) * C_ + co];
#pragma unroll
    for (int r = 0; r < 32; ++r) {
      float4 a = *(const float4*)&in_s[r][c4 * 4];
      acc[r] = fmaf(a.x, w0, fmaf(a.y, w1, fmaf(a.z, w2, fmaf(a.w, w3, acc[r]))));
    }
  }

  const float bi = bias[co];
#pragma unroll 4
  for (int r = 0; r < 32; ++r) {
    out[((size_t)b * S_TOT + s0 + r) * C_ + co] = fmaxf(acc[r] + bi, 0.f);
  }
}

// ---------------------------------------------------------------------------
// Kernel 2: fused scores + top-1-over-heads mask + online softmax stats.
// grid (36, 4, B), block 256, 64x64 tile, micro 4x4/thread x 8 heads.
// LDS 80 KiB (Q 64 KiB + K quarter 16 KiB) -> 2 blocks/CU at natural VGPR.
// ---------------------------------------------------------------------------
__global__ __launch_bounds__(256, 1) void k_scores(const float* __restrict__ Qp,
                                                   const float* __restrict__ Kp,
                                                   float* __restrict__ probs,
                                                   float* __restrict__ st_m,
                                                   float* __restrict__ st_z) {
  __shared__ __align__(16) float q_s[64 * 256];  // 64 KiB
  __shared__ __align__(16) float k_s[64 * 64];   // 16 KiB
  const int tid = threadIdx.x;
  const int i0 = blockIdx.x * 64;
  const int js = blockIdx.y;          // 0..3, chunk of 576 j's
  const int b  = blockIdx.z;
  const int jbase = js * 576;
  const int iq = tid >> 4;            // 0..15
  const int jq = tid & 15;            // 0..15

  for (int idx = tid; idx < 64 * 64; idx += 256) {
    int r = idx >> 6, c4 = idx & 63;
    float4 v = *(const float4*)(Qp + ((size_t)b * S_TOT + i0 + r) * C_ + c4 * 4);
    int c4s = (c4 & ~7) | ((c4 & 7) ^ (r & 7));
    *(float4*)&q_s[r * 256 + c4s * 4] = v;
  }

  float m_st[4][8], z_st[4][8];
#pragma unroll
  for (int v = 0; v < 4; ++v)
#pragma unroll
    for (int h = 0; h < 8; ++h) { m_st[v][h] = -1e18f; z_st[v][h] = 0.f; }

  for (int jt = 0; jt < 9; ++jt) {
    const int j0 = jbase + jt * 64;

    float sacc[4][4][8];
#pragma unroll
    for (int v = 0; v < 4; ++v)
#pragma unroll
      for (int u = 0; u < 4; ++u)
#pragma unroll
        for (int h = 0; h < 8; ++h) sacc[v][u][h] = 0.f;

#pragma unroll
    for (int cq = 0; cq < 4; ++cq) {
      __syncthreads();
      for (int e = tid; e < 1024; e += 256) {
        int r = e >> 4, c4k = e & 15;
        float4 v = *(const float4*)(Kp + ((size_t)b * S_TOT + j0 + r) * C_ + cq * 64 + c4k * 4);
        int c4s = (c4k & 8) | ((c4k & 7) ^ (r & 7));
        *(float4*)&k_s[r * 64 + c4s * 4] = v;
      }
      __syncthreads();

#pragma unroll
      for (int h2 = 0; h2 < 2; ++h2) {
        const int h = cq * 2 + h2;
#pragma unroll
        for (int cc = 0; cc < 8; ++cc) {
          float4 qv[4], kv[4];
#pragma unroll
          for (int v = 0; v < 4; ++v) {
            int r = iq + 16 * v;
            int c4s = (h * 8) | (cc ^ (r & 7));
            qv[v] = *(const float4*)&q_s[r * 256 + c4s * 4];
          }
#pragma unroll
          for (int u = 0; u < 4; ++u) {
            int r = jq + 16 * u;
            int c4s = (h2 * 8) | (cc ^ (r & 7));
            kv[u] = *(const float4*)&k_s[r * 64 + c4s * 4];
          }
#pragma unroll
          for (int v = 0; v < 4; ++v)
#pragma unroll
            for (int u = 0; u < 4; ++u) {
              sacc[v][u][h] = fmaf(qv[v].x, kv[u].x,
                               fmaf(qv[v].y, kv[u].y,
                                 fmaf(qv[v].z, kv[u].z,
                                   fmaf(qv[v].w, kv[u].w, sacc[v][u][h]))));
            }
        }
      }
    }

#pragma unroll
    for (int v = 0; v < 4; ++v) {
      const int i = i0 + iq + 16 * v;
#pragma unroll
      for (int u = 0; u < 4; ++u) {
        const int j = j0 + jq + 16 * u;
        float sc[8];
        float thr = -1e30f;
#pragma unroll
        for (int h = 0; h < 8; ++h) {
          sc[h] = sacc[v][u][h] * INV_SQRT_DH;
          thr = fmaxf(thr, sc[h]);
        }
#pragma unroll
        for (int h = 0; h < 8; ++h) {
          float mv = sc[h] < thr ? -1e18f : sc[h];
          probs[((size_t)((b * 8 + h) * S_TOT + i)) * S_TOT + j] = mv;
          float om = m_st[v][h];
          float d = mv - om;
          bool up = d > 0.f;
          float e = __expf(up ? -d : d);
          float z = z_st[v][h];
          z_st[v][h] = up ? fmaf(z, e, 1.f) : z + e;
          m_st[v][h] = up ? mv : om;
        }
      }
    }
  }

#pragma unroll
  for (int v = 0; v < 4; ++v) {
#pragma unroll
    for (int h = 0; h < 8; ++h) {
      float m = m_st[v][h], z = z_st[v][h];
#pragma unroll
      for (int off = 8; off >= 1; off >>= 1) {
        float m2 = __shfl_xor(m, off, 16);
        float z2 = __shfl_xor(z, off, 16);
        float nm = fmaxf(m, m2);
        z = fmaf(z, __expf(m - nm), z2 * __expf(m2 - nm));
        m = nm;
      }
      if (jq == 0) {
        const int i = i0 + iq + 16 * v;
        size_t sidx = ((size_t)(js * B_ + b) * HEADS_ + h) * S_TOT + i;
        st_m[sidx] = m;
        st_z[sidx] = z;
      }
    }
  }
}

// ---------------------------------------------------------------------------
// Kernel 3 (v2): probs finalize (in-place, float4) + ctx = probs @ V.
// grid (36 i-tiles, 8 h, 2 b) = 576 blocks, block 256 (4 waves).
// Per j-tile 64: stage p 64x64 (exp-finalized, XOR-swizzled) + V 64x32 (pad 40).
// Thread: ig(8) x dg(4) x jg(8, across waves); micro 8i x 8j x 8d, acc 64 regs.
// ---------------------------------------------------------------------------
__global__ __launch_bounds__(256) void k_pv(const float* __restrict__ Vp,
                                            const float* __restrict__ st_m,
                                            const float* __restrict__ st_z,
                                            float* __restrict__ probs,
                                            float* __restrict__ ctx) {
  __shared__ __align__(16) float p_s[64 * 64];   // 16 KB, quad-swizzled by (row>>3)
  __shared__ __align__(16) float v_s[64 * 40];   // 10 KB (also reduce buffer)
  __shared__ float row_m[64], row_iz[64];
  const int tid = threadIdx.x;
  const int w = tid >> 6, lane = tid & 63;
  const int ig = lane & 7;
  const int dg = (lane >> 3) & 3;
  const int jg_w = lane >> 5;
  const int jg = w * 2 + jg_w;        // 0..7
  const int i0 = blockIdx.x * 64;
  const int h  = blockIdx.y;
  const int b  = blockIdx.z;

  if (tid < 64) {
    const int i = i0 + tid;
    float mm[4], zz[4];
#pragma unroll
    for (int js = 0; js < 4; ++js) {
      size_t sidx = ((size_t)(js * B_ + b) * HEADS_ + h) * S_TOT + i;
      mm[js] = st_m[sidx];
      zz[js] = st_z[sidx];
    }
    float M = fmaxf(fmaxf(mm[0], mm[1]), fmaxf(mm[2], mm[3]));
    float Z = zz[0] * __expf(mm[0] - M) + zz[1] * __expf(mm[1] - M) +
              zz[2] * __expf(mm[2] - M) + zz[3] * __expf(mm[3] - M);
    row_m[tid] = M;
    row_iz[tid] = 1.0f / Z;
  }
  __syncthreads();

  float4 acc[8][2];
#pragma unroll
  for (int ii = 0; ii < 8; ++ii)
#pragma unroll
    for (int dq = 0; dq < 2; ++dq) acc[ii][dq] = make_float4(0.f, 0.f, 0.f, 0.f);

  float* pbase = probs + ((size_t)(b * 8 + h) * S_TOT + i0) * S_TOT;
  const float* vbase = Vp + (size_t)b * S_TOT * C_ + h * 32;

  for (int j0 = 0; j0 < S_TOT; j0 += 64) {
    // stage p (finalize exp in flight, write back global, store swizzled LDS)
#pragma unroll
    for (int k = 0; k < 4; ++k) {
      int e = tid + k * 256;
      int r = e >> 4, c4 = e & 15;
      float* gp = pbase + (size_t)r * S_TOT + j0 + c4 * 4;
      float4 sv = *(const float4*)gp;
      float M = row_m[r], iz = row_iz[r];
      float4 p;
      p.x = __expf(sv.x - M) * iz;
      p.y = __expf(sv.y - M) * iz;
      p.z = __expf(sv.z - M) * iz;
      p.w = __expf(sv.w - M) * iz;
      *(float4*)gp = p;
      int c4s = c4 ^ ((r >> 3) & 7);
      *(float4*)&p_s[r * 64 + c4s * 4] = p;
    }
    // stage V [64][40]
#pragma unroll
    for (int k = 0; k < 2; ++k) {
      int e = tid + k * 256;
      int j = e >> 3, d4 = e & 7;
      float4 v = *(const float4*)(vbase + (size_t)(j0 + j) * C_ + d4 * 4);
      *(float4*)&v_s[j * 40 + d4 * 4] = v;
    }
    __syncthreads();

#pragma unroll
    for (int jq4 = 0; jq4 < 2; ++jq4) {
      float4 vv[4][2];
#pragma unroll
      for (int jj = 0; jj < 4; ++jj) {
        const float* vp = &v_s[(jg * 8 + jq4 * 4 + jj) * 40 + dg * 8];
        vv[jj][0] = *(const float4*)vp;
        vv[jj][1] = *(const float4*)(vp + 4);
      }
#pragma unroll
      for (int ii = 0; ii < 8; ++ii) {
        int cq = (2 * jg + jq4) ^ ig;
        float4 p4 = *(const float4*)&p_s[(ig * 8 + ii) * 64 + cq * 4];
#pragma unroll
        for (int dq = 0; dq < 2; ++dq) {
          float4 a = acc[ii][dq];
          a.x = fmaf(p4.x, vv[0][dq].x, fmaf(p4.y, vv[1][dq].x, fmaf(p4.z, vv[2][dq].x, fmaf(p4.w, vv[3][dq].x, a.x))));
          a.y = fmaf(p4.x, vv[0][dq].y, fmaf(p4.y, vv[1][dq].y, fmaf(p4.z, vv[2][dq].y, fmaf(p4.w, vv[3][dq].y, a.y))));
          a.z = fmaf(p4.x, vv[0][dq].z, fmaf(p4.y, vv[1][dq].z, fmaf(p4.z, vv[2][dq].z, fmaf(p4.w, vv[3][dq].z, a.z))));
          a.w = fmaf(p4.x, vv[0][dq].w, fmaf(p4.y, vv[1][dq].w, fmaf(p4.z, vv[2][dq].w, fmaf(p4.w, vv[3][dq].w, a.w))));
          acc[ii][dq] = a;
        }
      }
    }
    __syncthreads();
  }

  // reduce over jg: in-wave pair (lane^32), then 4 wave-rounds into v_s
#pragma unroll
  for (int ii = 0; ii < 8; ++ii)
#pragma unroll
    for (int dq = 0; dq < 2; ++dq) {
      acc[ii][dq].x += __shfl_xor(acc[ii][dq].x, 32);
      acc[ii][dq].y += __shfl_xor(acc[ii][dq].y, 32);
      acc[ii][dq].z += __shfl_xor(acc[ii][dq].z, 32);
      acc[ii][dq].w += __shfl_xor(acc[ii][dq].w, 32);
    }
  for (int r = 0; r < 4; ++r) {
    __syncthreads();
    if (w == r && jg_w == 0) {
#pragma unroll
      for (int ii = 0; ii < 8; ++ii)
#pragma unroll
        for (int dq = 0; dq < 2; ++dq) {
          float4* dst = (float4*)&v_s[(ig * 8 + ii) * 40 + dg * 8 + dq * 4];
          if (r == 0) *dst = acc[ii][dq];
          else {
            float4 o = *dst;
            o.x += acc[ii][dq].x; o.y += acc[ii][dq].y;
            o.z += acc[ii][dq].z; o.w += acc[ii][dq].w;
            *dst = o;
          }
        }
    }
  }
  __syncthreads();

#pragma unroll
  for (int t = 0; t < 8; ++t) {
    int idx = tid + t * 256;
    int i = idx & 63, d = idx >> 6;
    ctx[((size_t)(b * 256 + h * 32 + d)) * S_TOT + i0 + i] = v_s[i * 40 + d];
  }
}

// ---------------------------------------------------------------------------
// Kernel 4a: repack conv weights W[co][ci][3][3] -> Wt[ci][k][co]
// ---------------------------------------------------------------------------
__global__ __launch_bounds__(256) void k_repackW(const float* __restrict__ W,
                                                 float* __restrict__ Wt) {
  const int ci = blockIdx.x;
  const int k  = blockIdx.y;
  const int co = threadIdx.x;
  Wt[((size_t)ci * 9 + k) * 256 + co] = W[((size_t)co * 256 + ci) * 9 + k];
}

// ---------------------------------------------------------------------------
// Kernel 4b (v3): 3x3 SAME conv. grid (8 co-tiles, 48 rows, 2 b) = 768 blocks.
// Block: 32 co x 1 row x 48 cols; ci split 8x across half-waves.
// Thread: cog(8 co-quads) x colg(4 groups of 12 px) x cig(8); micro 4co x 12px.
// Input LDS: image col c at 5+c -> 12-px window starts quad-aligned (12colg+4).
// W LDS padded to 36 floats/row.
// ---------------------------------------------------------------------------
template<bool DO_SELU>
__global__ __launch_bounds__(256) void k_conv3(const float* __restrict__ in,
                                               const float* __restrict__ Wt,
                                               const float* __restrict__ bias,
                                               float* __restrict__ out) {
  __shared__ __align__(16) float w_s[16 * 9 * 36];   // 20.7 KB (reduce buf reuse)
  __shared__ __align__(16) float in_s[16 * 3 * 56];  // 10.8 KB
  const int tid = threadIdx.x;
  const int w = tid >> 6, lane = tid & 63;
  const int cog  = lane & 7;
  const int colg = (lane >> 3) & 3;
  const int cig  = w * 2 + (lane >> 5);   // 0..7
  const int co0 = blockIdx.x * 32;
  const int row = blockIdx.y;
  const int b   = blockIdx.z;

  // zero halo cols {0..4, 53..55} for all 48 (ci,r) rows
  for (int e = tid; e < 48 * 8; e += 256) {
    int rr_ = e >> 3, c = e & 7;
    in_s[rr_ * 56 + (c < 5 ? c : 48 + c)] = 0.f;
  }

  float4 acc[12];
#pragma unroll
  for (int p = 0; p < 12; ++p) acc[p] = make_float4(0.f, 0.f, 0.f, 0.f);

  for (int s = 0; s < 16; ++s) {
    __syncthreads();
    // stage W: 16 ci x 9 k x 32 co
    for (int e = tid; e < 1152; e += 256) {
      int coq = e & 7, t = e >> 3;
      int k = t % 9, cc = t / 9;              // cc 0..15
      int ci = cc & 1, cg = cc >> 1;
      float4 v = *(const float4*)(Wt + (((size_t)(cg * 32 + s * 2 + ci) * 9 + k) * 256 + co0 + coq * 4));
      *(float4*)&w_s[((cg * 2 + ci) * 9 + k) * 36 + coq * 4] = v;
    }
    // stage input: 16 ci x 3 rows x 48 cols (scalar, coalesced)
    for (int e = tid; e < 2304; e += 256) {
      int col = e % 48; int t = e / 48;
      int r = t % 3; int cc = t / 3;          // cc 0..15
      int ci = cc & 1, cg = cc >> 1;
      int gr = row - 1 + r;
      float v = 0.f;
      if (gr >= 0 && gr < 48)
        v = in[((size_t)(b * 256 + cg * 32 + s * 2 + ci) * 48 + gr) * 48 + col];
      in_s[((cg * 2 + ci) * 3 + r) * 56 + 5 + col] = v;
    }
    __syncthreads();

#pragma unroll
    for (int ci = 0; ci < 2; ++ci) {
      const float* wb = &w_s[((cig * 2 + ci) * 9) * 36 + cog * 4];
      float4 wv[9];
#pragma unroll
      for (int k = 0; k < 9; ++k) wv[k] = *(const float4*)&wb[k * 36];
      float rr[3][16];
#pragma unroll
      for (int r = 0; r < 3; ++r) {
        const float* ib = &in_s[((cig * 2 + ci) * 3 + r) * 56 + 12 * colg + 4];
        *(float4*)&rr[r][0]  = *(const float4*)&ib[0];
        *(float4*)&rr[r][4]  = *(const float4*)&ib[4];
        *(float4*)&rr[r][8]  = *(const float4*)&ib[8];
        *(float4*)&rr[r][12] = *(const float4*)&ib[12];
      }
#pragma unroll
      for (int ky = 0; ky < 3; ++ky)
#pragma unroll
        for (int kx = 0; kx < 3; ++kx) {
          float4 w4 = wv[ky * 3 + kx];
#pragma unroll
          for (int p = 0; p < 12; ++p) {
            float rv = rr[ky][p + kx];
            acc[p].x = fmaf(rv, w4.x, acc[p].x);
            acc[p].y = fmaf(rv, w4.y, acc[p].y);
            acc[p].z = fmaf(rv, w4.z, acc[p].z);
            acc[p].w = fmaf(rv, w4.w, acc[p].w);
          }
        }
    }
  }

  // reduce across cig: in-wave half pair, then 4 wave-rounds into w_s region
#pragma unroll
  for (int p = 0; p < 12; ++p) {
    acc[p].x += __shfl_xor(acc[p].x, 32);
    acc[p].y += __shfl_xor(acc[p].y, 32);
    acc[p].z += __shfl_xor(acc[p].z, 32);
    acc[p].w += __shfl_xor(acc[p].w, 32);
  }
  float* red = w_s;  // [48 px][36] (co padded)
  for (int r = 0; r < 4; ++r) {
    __syncthreads();
    if (w == r && (lane >> 5) == 0) {
#pragma unroll
      for (int p = 0; p < 12; ++p) {
        float4* dst = (float4*)&red[(colg * 12 + p) * 36 + cog * 4];
        if (r == 0) *dst = acc[p];
        else {
          float4 o = *dst;
          o.x += acc[p].x; o.y += acc[p].y; o.z += acc[p].z; o.w += acc[p].w;
          *dst = o;
        }
      }
    }
  }
  __syncthreads();

  for (int e = tid; e < 1536; e += 256) {
    int col = e % 48, co_l = e / 48;
    float y = red[col * 36 + co_l] + bias[co0 + co_l];
    if (DO_SELU)
      y = 1.0507009873554805f * (y > 0.f ? y : 1.6732632423543772f * expm1f(y));
    out[((size_t)(b * 256 + co0 + co_l) * 48 + row) * 48 + col] = y;
  }
}

// ---------------------------------------------------------------------------
extern "C" void kernel_launch(void* const* d_in, const int* in_sizes, int n_in,
                              void* d_out, int out_size, void* d_ws, size_t ws_size,
                              hipStream_t stream) {
  const float* x   = (const float*)d_in[0];
  const float* ref = (const float*)d_in[1];
  const float* qW1 = (const float*)d_in[2];
  const float* qb1 = (const float*)d_in[3];
  const float* qW2 = (const float*)d_in[4];
  const float* qb2 = (const float*)d_in[5];
  const float* kW1 = (const float*)d_in[6];
  const float* kb1 = (const float*)d_in[7];
  const float* kW2 = (const float*)d_in[8];
  const float* kb2 = (const float*)d_in[9];
  const float* vW1 = (const float*)d_in[10];
  const float* vb1 = (const float*)d_in[11];
  const float* vW2 = (const float*)d_in[12];
  const float* vb2 = (const float*)d_in[13];
  const float* c1W = (const float*)d_in[14];
  const float* c1b = (const float*)d_in[15];
  const float* c2W = (const float*)d_in[16];
  const float* c2b = (const float*)d_in[17];

  float* out = (float*)d_out;
  float* probs = out + (size_t)B_ * C_ * S_TOT;       // [B][H][S][S]
  float* ws = (float*)d_ws;
  const size_t BSC = (size_t)B_ * S_TOT * C_;         // 1,179,648
  const size_t STATS = (size_t)4 * B_ * HEADS_ * S_TOT;
  const size_t WTSZ = (size_t)256 * 9 * 256;          // 589,824

  float* Qb  = ws;
  float* Kb  = Qb + BSC;
  float* Vb  = Kb + BSC;
  float* Ht  = Vb + BSC;
  float* stm = Ht + BSC;
  float* stz = stm + STATS;
  float* ctx = stz + STATS;
  float* tmp1 = ctx + BSC;
  float* Wt1 = tmp1 + BSC;
  float* Wt2 = Wt1 + WTSZ;

  dim3 blk(256);
  k_repackW<<<dim3(256, 9), blk, 0, stream>>>(c1W, Wt1);
  k_repackW<<<dim3(256, 9), blk, 0, stream>>>(c2W, Wt2);

  dim3 gmlp(72, B_);
  k_mlp<0><<<gmlp, blk, 0, stream>>>(x,   qW1, qb1, Ht);
  k_mlp<1><<<gmlp, blk, 0, stream>>>(Ht,  qW2, qb2, Qb);
  k_mlp<0><<<gmlp, blk, 0, stream>>>(ref, kW1, kb1, Ht);
  k_mlp<1><<<gmlp, blk, 0, stream>>>(Ht,  kW2, kb2, Kb);
  k_mlp<0><<<gmlp, blk, 0, stream>>>(ref, vW1, vb1, Ht);
  k_mlp<1><<<gmlp, blk, 0, stream>>>(Ht,  vW2, vb2, Vb);

  k_scores<<<dim3(36, 4, B_), blk, 0, stream>>>(Qb, Kb, probs, stm, stz);
  k_pv<<<dim3(36, 8, B_), blk, 0, stream>>>(Vb, stm, stz, probs, ctx);
  k_conv3<true ><<<dim3(8, 48, B_), blk, 0, stream>>>(ctx,  Wt1, c1b, tmp1);
  k_conv3<false><<<dim3(8, 48, B_), blk, 0, stream>>>(tmp1, Wt2, c2b, out);
}

// Round 5
// 1104.169 us; speedup vs baseline: 1.4013x; 1.2045x over previous
//
#include <hip/hip_runtime.h>
#include <hip/hip_bf16.h>

typedef unsigned short ushort_t;
typedef short s8v __attribute__((ext_vector_type(8)));   // 8 bf16 bit-patterns
typedef float f32x4 __attribute__((ext_vector_type(4)));

// Problem constants
constexpr int B_ = 2;
constexpr int C_ = 256;
constexpr int S_TOT = 48 * 48;   // 2304
constexpr int HEADS_ = 8;
#define INV_SQRT_DH 0.17677669529663688f

// ---------------------------------------------------------------------------
// Kernel 1: MLP layer  out[b][s][co] = relu( sum_ci in[b][s][ci]*W[ci][co] + b )
// IN_MODE 0: in is [B][C][S]; IN_MODE 1: in is [B][S][C]
// ---------------------------------------------------------------------------
template<int IN_MODE>
__global__ __launch_bounds__(256) void k_mlp(const float* __restrict__ in,
                                             const float* __restrict__ Wm,
                                             const float* __restrict__ bias,
                                             float* __restrict__ out) {
  __shared__ __align__(16) float in_s[32][260];
  const int tid = threadIdx.x;
  const int s0 = blockIdx.x * 32;
  const int b  = blockIdx.y;

  if (IN_MODE == 0) {
    for (int idx = tid; idx < 32 * 256; idx += 256) {
      int ci = idx >> 5, r = idx & 31;
      in_s[r][ci] = in[((size_t)b * C_ + ci) * S_TOT + s0 + r];
    }
  } else {
    for (int idx = tid; idx < 32 * 256; idx += 256) {
      int r = idx >> 8, ci = idx & 255;
      in_s[r][ci] = in[((size_t)b * S_TOT + s0 + r) * C_ + ci];
    }
  }
  __syncthreads();

  const int co = tid;
  float acc[32];
#pragma unroll
  for (int r = 0; r < 32; ++r) acc[r] = 0.f;

  for (int c4 = 0; c4 < 64; ++c4) {
    const float w0 = Wm[(c4 * 4 + 0) * C_ + co];
    const float w1 = Wm[(c4 * 4 + 1) * C_ + co];
    const float w2 = Wm[(c4 * 4 + 2) * C_ + co];
    const float w3 = Wm[(c4 * 4 + 3) * C_ + co];
#pragma unroll
    for (int r = 0; r < 32; ++r) {
      float4 a = *(const float4*)&in_s[r][c4 * 4];
      acc[r] = fmaf(a.x, w0, fmaf(a.y, w1, fmaf(a.z, w2, fmaf(a.w, w3, acc[r]))));
    }
  }

  const float bi = bias[co];
#pragma unroll 4
  for (int r = 0; r < 32; ++r) {
    out[((size_t)b * S_TOT + s0 + r) * C_ + co] = fmaxf(acc[r] + bi, 0.f);
  }
}

// ---------------------------------------------------------------------------
// Kernel 1b: split f32 -> (bf16 hi, bf16 lo) planes. n multiple of 1024.
// ---------------------------------------------------------------------------
__device__ __forceinline__ ushort_t bf16_rn(float x) {
  unsigned u = __float_as_uint(x);
  return (ushort_t)((u + 0x7fffu + ((u >> 16) & 1u)) >> 16);
}

__global__ __launch_bounds__(256) void k_split(const float* __restrict__ in,
                                               ushort_t* __restrict__ hi,
                                               ushort_t* __restrict__ lo) {
  size_t idx = ((size_t)blockIdx.x * 256 + threadIdx.x) * 4;
  float4 v = *(const float4*)(in + idx);
  ushort_t h0 = bf16_rn(v.x), h1 = bf16_rn(v.y), h2 = bf16_rn(v.z), h3 = bf16_rn(v.w);
  float r0 = __uint_as_float((unsigned)h0 << 16);
  float r1 = __uint_as_float((unsigned)h1 << 16);
  float r2 = __uint_as_float((unsigned)h2 << 16);
  float r3 = __uint_as_float((unsigned)h3 << 16);
  ushort_t l0 = bf16_rn(v.x - r0), l1 = bf16_rn(v.y - r1);
  ushort_t l2 = bf16_rn(v.z - r2), l3 = bf16_rn(v.w - r3);
  ushort4 hv; hv.x = h0; hv.y = h1; hv.z = h2; hv.w = h3;
  ushort4 lv; lv.x = l0; lv.y = l1; lv.z = l2; lv.w = l3;
  *(ushort4*)(hi + idx) = hv;
  *(ushort4*)(lo + idx) = lv;
}

// ---------------------------------------------------------------------------
// Kernel 2 (MFMA): scores = (Q.K^T)/sqrt(dh), all 8 heads, top-1-over-heads
// mask, masked-score write, per-row z = sum(exp(masked)) (no max shift;
// scores are O(1), masked -> exp(-1e18)=0 exactly).
// Split-bf16 emulation: 3 x mfma_f32_16x16x32_bf16 per 16x16 tile.
// grid (36 i-tiles, 4 j-chunks, B), block 256 = 4 waves; wave w owns i-band
// of 16 rows, holds all 8 heads' A-frags (hi+lo) in regs for whole kernel.
// K tile (hi+lo) in LDS 64 KiB -> 2 blocks/CU. A and B frags use identical
// lane->k maps, so the k-permutation cancels in the dot product.
// ---------------------------------------------------------------------------
__global__ __launch_bounds__(256) void k_scores_mfma(
    const ushort_t* __restrict__ Qh, const ushort_t* __restrict__ Ql,
    const ushort_t* __restrict__ Kh, const ushort_t* __restrict__ Kl,
    float* __restrict__ probs, float* __restrict__ st_m,
    float* __restrict__ st_z) {
  __shared__ __align__(16) uint4 kh_s[64 * 32];  // 32 KiB, chunk idx ^ (r&7)
  __shared__ __align__(16) uint4 kl_s[64 * 32];  // 32 KiB
  const int tid = threadIdx.x;
  const int w = tid >> 6, lane = tid & 63;
  const int li = lane & 15, kg = lane >> 4;      // C: col=li, rows=kg*4+reg
  const int i0 = blockIdx.x * 64;
  const int js = blockIdx.y;
  const int b  = blockIdx.z;
  const int jbase = js * 576;

  // A-frags: row = i0 + w*16 + li, k-chunk kg*8, per head h (hi+lo), resident.
  s8v ahi[8], alo[8];
  {
    const ushort_t* qh = Qh + ((size_t)b * S_TOT + i0 + w * 16 + li) * C_ + kg * 8;
    const ushort_t* ql = Ql + ((size_t)b * S_TOT + i0 + w * 16 + li) * C_ + kg * 8;
#pragma unroll
    for (int h = 0; h < 8; ++h) {
      ahi[h] = __builtin_bit_cast(s8v, *(const uint4*)(qh + h * 32));
      alo[h] = __builtin_bit_cast(s8v, *(const uint4*)(ql + h * 32));
    }
  }

  float zacc[4][8];
#pragma unroll
  for (int r = 0; r < 4; ++r)
#pragma unroll
    for (int h = 0; h < 8; ++h) zacc[r][h] = 0.f;

  for (int jt = 0; jt < 9; ++jt) {
    const int j0 = jbase + jt * 64;
    __syncthreads();
    for (int e = tid; e < 2048; e += 256) {
      int r = e >> 5, c = e & 31;
      size_t goff = ((size_t)b * S_TOT + j0 + r) * C_ + c * 8;
      int cs = c ^ (r & 7);
      kh_s[r * 32 + cs] = *(const uint4*)(Kh + goff);
      kl_s[r * 32 + cs] = *(const uint4*)(Kl + goff);
    }
    __syncthreads();

#pragma unroll
    for (int jsub = 0; jsub < 4; ++jsub) {
      const int rj = jsub * 16 + li;
      f32x4 sc[8];
#pragma unroll
      for (int h = 0; h < 8; ++h) {
        const int cs = (h * 4 + kg) ^ (rj & 7);
        s8v bhi = __builtin_bit_cast(s8v, kh_s[rj * 32 + cs]);
        s8v blo = __builtin_bit_cast(s8v, kl_s[rj * 32 + cs]);
        f32x4 acc = {0.f, 0.f, 0.f, 0.f};
        acc = __builtin_amdgcn_mfma_f32_16x16x32_bf16(ahi[h], bhi, acc, 0, 0, 0);
        acc = __builtin_amdgcn_mfma_f32_16x16x32_bf16(ahi[h], blo, acc, 0, 0, 0);
        acc = __builtin_amdgcn_mfma_f32_16x16x32_bf16(alo[h], bhi, acc, 0, 0, 0);
        sc[h] = acc;
      }
      const int jcol = j0 + jsub * 16 + li;
#pragma unroll
      for (int reg = 0; reg < 4; ++reg) {
        float s8_[8];
        float thr = -1e30f;
#pragma unroll
        for (int h = 0; h < 8; ++h) {
          s8_[h] = sc[h][reg] * INV_SQRT_DH;
          thr = fmaxf(thr, s8_[h]);
        }
        const int i = i0 + w * 16 + kg * 4 + reg;
#pragma unroll
        for (int h = 0; h < 8; ++h) {
          float mv = s8_[h] < thr ? -1e18f : s8_[h];
          probs[((size_t)((b * 8 + h) * S_TOT + i)) * S_TOT + jcol] = mv;
          zacc[reg][h] += __expf(mv);   // exp(-1e18) == 0 exactly
        }
      }
    }
  }

  // reduce z across the 16 lanes of the li group (same rows)
#pragma unroll
  for (int reg = 0; reg < 4; ++reg) {
#pragma unroll
    for (int h = 0; h < 8; ++h) {
      float z = zacc[reg][h];
      z += __shfl_xor(z, 1);
      z += __shfl_xor(z, 2);
      z += __shfl_xor(z, 4);
      z += __shfl_xor(z, 8);
      if (li == 0) {
        const int i = i0 + w * 16 + kg * 4 + reg;
        size_t sidx = ((size_t)(js * B_ + b) * HEADS_ + h) * S_TOT + i;
        st_z[sidx] = z;
        st_m[sidx] = 0.f;
      }
    }
  }
}

// ---------------------------------------------------------------------------
// Kernel 3: probs finalize (in-place, float4) + ctx = probs @ V.
// grid (36 i-tiles, 8 h, 2 b) = 576 blocks, block 256 (4 waves).
// ---------------------------------------------------------------------------
__global__ __launch_bounds__(256) void k_pv(const float* __restrict__ Vp,
                                            const float* __restrict__ st_m,
                                            const float* __restrict__ st_z,
                                            float* __restrict__ probs,
                                            float* __restrict__ ctx) {
  __shared__ __align__(16) float p_s[64 * 64];   // 16 KB, quad-swizzled
  __shared__ __align__(16) float v_s[64 * 40];   // 10 KB (also reduce buffer)
  __shared__ float row_m[64], row_iz[64];
  const int tid = threadIdx.x;
  const int w = tid >> 6, lane = tid & 63;
  const int ig = lane & 7;
  const int dg = (lane >> 3) & 3;
  const int jg_w = lane >> 5;
  const int jg = w * 2 + jg_w;        // 0..7
  const int i0 = blockIdx.x * 64;
  const int h  = blockIdx.y;
  const int b  = blockIdx.z;

  if (tid < 64) {
    const int i = i0 + tid;
    float mm[4], zz[4];
#pragma unroll
    for (int js = 0; js < 4; ++js) {
      size_t sidx = ((size_t)(js * B_ + b) * HEADS_ + h) * S_TOT + i;
      mm[js] = st_m[sidx];
      zz[js] = st_z[sidx];
    }
    float M = fmaxf(fmaxf(mm[0], mm[1]), fmaxf(mm[2], mm[3]));
    float Z = zz[0] * __expf(mm[0] - M) + zz[1] * __expf(mm[1] - M) +
              zz[2] * __expf(mm[2] - M) + zz[3] * __expf(mm[3] - M);
    if (Z == 0.f) {                   // fully-masked row: uniform (ref behavior)
      row_m[tid] = -1e18f;
      row_iz[tid] = 1.0f / (float)S_TOT;
    } else {
      row_m[tid] = M;
      row_iz[tid] = 1.0f / Z;
    }
  }
  __syncthreads();

  float4 acc[8][2];
#pragma unroll
  for (int ii = 0; ii < 8; ++ii)
#pragma unroll
    for (int dq = 0; dq < 2; ++dq) acc[ii][dq] = make_float4(0.f, 0.f, 0.f, 0.f);

  float* pbase = probs + ((size_t)(b * 8 + h) * S_TOT + i0) * S_TOT;
  const float* vbase = Vp + (size_t)b * S_TOT * C_ + h * 32;

  for (int j0 = 0; j0 < S_TOT; j0 += 64) {
#pragma unroll
    for (int k = 0; k < 4; ++k) {
      int e = tid + k * 256;
      int r = e >> 4, c4 = e & 15;
      float* gp = pbase + (size_t)r * S_TOT + j0 + c4 * 4;
      float4 sv = *(const float4*)gp;
      float M = row_m[r], iz = row_iz[r];
      float4 p;
      p.x = __expf(sv.x - M) * iz;
      p.y = __expf(sv.y - M) * iz;
      p.z = __expf(sv.z - M) * iz;
      p.w = __expf(sv.w - M) * iz;
      *(float4*)gp = p;
      int c4s = c4 ^ ((r >> 3) & 7);
      *(float4*)&p_s[r * 64 + c4s * 4] = p;
    }
#pragma unroll
    for (int k = 0; k < 2; ++k) {
      int e = tid + k * 256;
      int j = e >> 3, d4 = e & 7;
      float4 v = *(const float4*)(vbase + (size_t)(j0 + j) * C_ + d4 * 4);
      *(float4*)&v_s[j * 40 + d4 * 4] = v;
    }
    __syncthreads();

#pragma unroll
    for (int jq4 = 0; jq4 < 2; ++jq4) {
      float4 vv[4][2];
#pragma unroll
      for (int jj = 0; jj < 4; ++jj) {
        const float* vp = &v_s[(jg * 8 + jq4 * 4 + jj) * 40 + dg * 8];
        vv[jj][0] = *(const float4*)vp;
        vv[jj][1] = *(const float4*)(vp + 4);
      }
#pragma unroll
      for (int ii = 0; ii < 8; ++ii) {
        int cq = (2 * jg + jq4) ^ ig;
        float4 p4 = *(const float4*)&p_s[(ig * 8 + ii) * 64 + cq * 4];
#pragma unroll
        for (int dq = 0; dq < 2; ++dq) {
          float4 a = acc[ii][dq];
          a.x = fmaf(p4.x, vv[0][dq].x, fmaf(p4.y, vv[1][dq].x, fmaf(p4.z, vv[2][dq].x, fmaf(p4.w, vv[3][dq].x, a.x))));
          a.y = fmaf(p4.x, vv[0][dq].y, fmaf(p4.y, vv[1][dq].y, fmaf(p4.z, vv[2][dq].y, fmaf(p4.w, vv[3][dq].y, a.y))));
          a.z = fmaf(p4.x, vv[0][dq].z, fmaf(p4.y, vv[1][dq].z, fmaf(p4.z, vv[2][dq].z, fmaf(p4.w, vv[3][dq].z, a.z))));
          a.w = fmaf(p4.x, vv[0][dq].w, fmaf(p4.y, vv[1][dq].w, fmaf(p4.z, vv[2][dq].w, fmaf(p4.w, vv[3][dq].w, a.w))));
          acc[ii][dq] = a;
        }
      }
    }
    __syncthreads();
  }

#pragma unroll
  for (int ii = 0; ii < 8; ++ii)
#pragma unroll
    for (int dq = 0; dq < 2; ++dq) {
      acc[ii][dq].x += __shfl_xor(acc[ii][dq].x, 32);
      acc[ii][dq].y += __shfl_xor(acc[ii][dq].y, 32);
      acc[ii][dq].z += __shfl_xor(acc[ii][dq].z, 32);
      acc[ii][dq].w += __shfl_xor(acc[ii][dq].w, 32);
    }
  for (int r = 0; r < 4; ++r) {
    __syncthreads();
    if (w == r && jg_w == 0) {
#pragma unroll
      for (int ii = 0; ii < 8; ++ii)
#pragma unroll
        for (int dq = 0; dq < 2; ++dq) {
          float4* dst = (float4*)&v_s[(ig * 8 + ii) * 40 + dg * 8 + dq * 4];
          if (r == 0) *dst = acc[ii][dq];
          else {
            float4 o = *dst;
            o.x += acc[ii][dq].x; o.y += acc[ii][dq].y;
            o.z += acc[ii][dq].z; o.w += acc[ii][dq].w;
            *dst = o;
          }
        }
    }
  }
  __syncthreads();

#pragma unroll
  for (int t = 0; t < 8; ++t) {
    int idx = tid + t * 256;
    int i = idx & 63, d = idx >> 6;
    ctx[((size_t)(b * 256 + h * 32 + d)) * S_TOT + i0 + i] = v_s[i * 40 + d];
  }
}

// ---------------------------------------------------------------------------
// Kernel 4a: repack conv weights W[co][ci][3][3] -> Wt[ci][k][co]
// ---------------------------------------------------------------------------
__global__ __launch_bounds__(256) void k_repackW(const float* __restrict__ W,
                                                 float* __restrict__ Wt) {
  const int ci = blockIdx.x;
  const int k  = blockIdx.y;
  const int co = threadIdx.x;
  Wt[((size_t)ci * 9 + k) * 256 + co] = W[((size_t)co * 256 + ci) * 9 + k];
}

// ---------------------------------------------------------------------------
// Kernel 4b: 3x3 SAME conv. grid (8 co-tiles, 48 rows, 2 b) = 768 blocks.
// ---------------------------------------------------------------------------
template<bool DO_SELU>
__global__ __launch_bounds__(256) void k_conv3(const float* __restrict__ in,
                                               const float* __restrict__ Wt,
                                               const float* __restrict__ bias,
                                               float* __restrict__ out) {
  __shared__ __align__(16) float w_s[16 * 9 * 36];
  __shared__ __align__(16) float in_s[16 * 3 * 56];
  const int tid = threadIdx.x;
  const int w = tid >> 6, lane = tid & 63;
  const int cog  = lane & 7;
  const int colg = (lane >> 3) & 3;
  const int cig  = w * 2 + (lane >> 5);   // 0..7
  const int co0 = blockIdx.x * 32;
  const int row = blockIdx.y;
  const int b   = blockIdx.z;

  for (int e = tid; e < 48 * 8; e += 256) {
    int rr_ = e >> 3, c = e & 7;
    in_s[rr_ * 56 + (c < 5 ? c : 48 + c)] = 0.f;
  }

  float4 acc[12];
#pragma unroll
  for (int p = 0; p < 12; ++p) acc[p] = make_float4(0.f, 0.f, 0.f, 0.f);

  for (int s = 0; s < 16; ++s) {
    __syncthreads();
    for (int e = tid; e < 1152; e += 256) {
      int coq = e & 7, t = e >> 3;
      int k = t % 9, cc = t / 9;
      int ci = cc & 1, cg = cc >> 1;
      float4 v = *(const float4*)(Wt + (((size_t)(cg * 32 + s * 2 + ci) * 9 + k) * 256 + co0 + coq * 4));
      *(float4*)&w_s[((cg * 2 + ci) * 9 + k) * 36 + coq * 4] = v;
    }
    for (int e = tid; e < 2304; e += 256) {
      int col = e % 48; int t = e / 48;
      int r = t % 3; int cc = t / 3;
      int ci = cc & 1, cg = cc >> 1;
      int gr = row - 1 + r;
      float v = 0.f;
      if (gr >= 0 && gr < 48)
        v = in[((size_t)(b * 256 + cg * 32 + s * 2 + ci) * 48 + gr) * 48 + col];
      in_s[((cg * 2 + ci) * 3 + r) * 56 + 5 + col] = v;
    }
    __syncthreads();

#pragma unroll
    for (int ci = 0; ci < 2; ++ci) {
      const float* wb = &w_s[((cig * 2 + ci) * 9) * 36 + cog * 4];
      float4 wv[9];
#pragma unroll
      for (int k = 0; k < 9; ++k) wv[k] = *(const float4*)&wb[k * 36];
      float rr[3][16];
#pragma unroll
      for (int r = 0; r < 3; ++r) {
        const float* ib = &in_s[((cig * 2 + ci) * 3 + r) * 56 + 12 * colg + 4];
        *(float4*)&rr[r][0]  = *(const float4*)&ib[0];
        *(float4*)&rr[r][4]  = *(const float4*)&ib[4];
        *(float4*)&rr[r][8]  = *(const float4*)&ib[8];
        *(float4*)&rr[r][12] = *(const float4*)&ib[12];
      }
#pragma unroll
      for (int ky = 0; ky < 3; ++ky)
#pragma unroll
        for (int kx = 0; kx < 3; ++kx) {
          float4 w4 = wv[ky * 3 + kx];
#pragma unroll
          for (int p = 0; p < 12; ++p) {
            float rv = rr[ky][p + kx];
            acc[p].x = fmaf(rv, w4.x, acc[p].x);
            acc[p].y = fmaf(rv, w4.y, acc[p].y);
            acc[p].z = fmaf(rv, w4.z, acc[p].z);
            acc[p].w = fmaf(rv, w4.w, acc[p].w);
          }
        }
    }
  }

#pragma unroll
  for (int p = 0; p < 12; ++p) {
    acc[p].x += __shfl_xor(acc[p].x, 32);
    acc[p].y += __shfl_xor(acc[p].y, 32);
    acc[p].z += __shfl_xor(acc[p].z, 32);
    acc[p].w += __shfl_xor(acc[p].w, 32);
  }
  float* red = w_s;
  for (int r = 0; r < 4; ++r) {
    __syncthreads();
    if (w == r && (lane >> 5) == 0) {
#pragma unroll
      for (int p = 0; p < 12; ++p) {
        float4* dst = (float4*)&red[(colg * 12 + p) * 36 + cog * 4];
        if (r == 0) *dst = acc[p];
        else {
          float4 o = *dst;
          o.x += acc[p].x; o.y += acc[p].y; o.z += acc[p].z; o.w += acc[p].w;
          *dst = o;
        }
      }
    }
  }
  __syncthreads();

  for (int e = tid; e < 1536; e += 256) {
    int col = e % 48, co_l = e / 48;
    float y = red[col * 36 + co_l] + bias[co0 + co_l];
    if (DO_SELU)
      y = 1.0507009873554805f * (y > 0.f ? y : 1.6732632423543772f * expm1f(y));
    out[((size_t)(b * 256 + co0 + co_l) * 48 + row) * 48 + col] = y;
  }
}

// ---------------------------------------------------------------------------
extern "C" void kernel_launch(void* const* d_in, const int* in_sizes, int n_in,
                              void* d_out, int out_size, void* d_ws, size_t ws_size,
                              hipStream_t stream) {
  const float* x   = (const float*)d_in[0];
  const float* ref = (const float*)d_in[1];
  const float* qW1 = (const float*)d_in[2];
  const float* qb1 = (const float*)d_in[3];
  const float* qW2 = (const float*)d_in[4];
  const float* qb2 = (const float*)d_in[5];
  const float* kW1 = (const float*)d_in[6];
  const float* kb1 = (const float*)d_in[7];
  const float* kW2 = (const float*)d_in[8];
  const float* kb2 = (const float*)d_in[9];
  const float* vW1 = (const float*)d_in[10];
  const float* vb1 = (const float*)d_in[11];
  const float* vW2 = (const float*)d_in[12];
  const float* vb2 = (const float*)d_in[13];
  const float* c1W = (const float*)d_in[14];
  const float* c1b = (const float*)d_in[15];
  const float* c2W = (const float*)d_in[16];
  const float* c2b = (const float*)d_in[17];

  float* out = (float*)d_out;
  float* probs = out + (size_t)B_ * C_ * S_TOT;       // [B][H][S][S]
  float* ws = (float*)d_ws;
  const size_t BSC = (size_t)B_ * S_TOT * C_;         // 1,179,648
  const size_t STATS = (size_t)4 * B_ * HEADS_ * S_TOT;
  const size_t WTSZ = (size_t)256 * 9 * 256;

  float* Qb  = ws;
  float* Kb  = Qb + BSC;
  float* Vb  = Kb + BSC;
  float* Ht  = Vb + BSC;
  float* stm = Ht + BSC;
  float* stz = stm + STATS;
  float* ctx = stz + STATS;
  float* tmp1 = ctx + BSC;
  float* Wt1 = tmp1 + BSC;
  float* Wt2 = Wt1 + WTSZ;

  // bf16 split planes live in recycled buffers: Q planes in Ht (free after
  // MLPs), K planes in Qb (free after Q split).
  ushort_t* QhP = (ushort_t*)Ht;
  ushort_t* QlP = QhP + BSC;
  ushort_t* KhP = (ushort_t*)Qb;
  ushort_t* KlP = KhP + BSC;

  dim3 blk(256);
  k_repackW<<<dim3(256, 9), blk, 0, stream>>>(c1W, Wt1);
  k_repackW<<<dim3(256, 9), blk, 0, stream>>>(c2W, Wt2);

  dim3 gmlp(72, B_);
  k_mlp<0><<<gmlp, blk, 0, stream>>>(x,   qW1, qb1, Ht);
  k_mlp<1><<<gmlp, blk, 0, stream>>>(Ht,  qW2, qb2, Qb);
  k_mlp<0><<<gmlp, blk, 0, stream>>>(ref, kW1, kb1, Ht);
  k_mlp<1><<<gmlp, blk, 0, stream>>>(Ht,  kW2, kb2, Kb);
  k_mlp<0><<<gmlp, blk, 0, stream>>>(ref, vW1, vb1, Ht);
  k_mlp<1><<<gmlp, blk, 0, stream>>>(Ht,  vW2, vb2, Vb);

  const int nsplit = (int)(BSC / 4 / 256);            // 1152 blocks
  k_split<<<dim3(nsplit), blk, 0, stream>>>(Qb, QhP, QlP);  // Q -> Ht space
  k_split<<<dim3(nsplit), blk, 0, stream>>>(Kb, KhP, KlP);  // K -> Qb space

  k_scores_mfma<<<dim3(36, 4, B_), blk, 0, stream>>>(QhP, QlP, KhP, KlP,
                                                     probs, stm, stz);
  k_pv<<<dim3(36, 8, B_), blk, 0, stream>>>(Vb, stm, stz, probs, ctx);
  k_conv3<true ><<<dim3(8, 48, B_), blk, 0, stream>>>(ctx,  Wt1, c1b, tmp1);
  k_conv3<false><<<dim3(8, 48, B_), blk, 0, stream>>>(tmp1, Wt2, c2b, out);
}